// Round 2
// baseline (560.475 us; speedup 1.0000x reference)
//
#include <hip/hip_runtime.h>

// FM with per-field tables:
// x:   (16384, 20) int32, emb: (20, 100000, 64) fp32
// out[b] = sum_f x[b,f] + 0.5*(||sum_f v_f||^2 - sum_f ||v_f||^2)

constexpr int BATCH        = 16384;
constexpr int NUM_FIELDS   = 20;
constexpr int NUM_FEATURES = 100000;
constexpr int LATENT       = 64;

// One wave per row. lane = q*16 + r;  q in [0,4) = field phase, r in [0,16) = dim group.
// Iteration i: lane loads float4 of emb[4i+q, x[row,4i+q], 4r..4r+3]
// -> one dwordx4/lane = 1 KB/wave = 4 complete 256B field rows per instruction.
__global__ __launch_bounds__(256)
void ffm_kernel(const int* __restrict__ x,
                const float* __restrict__ emb,
                float* __restrict__ out) {
    const int wave = threadIdx.x >> 6;
    const int lane = threadIdx.x & 63;
    const int row  = blockIdx.x * 4 + wave;

    const int q = lane >> 4;   // field phase
    const int r = lane & 15;   // dim group (dims 4r..4r+3)

    const int* xr = x + row * NUM_FIELDS;

    float4 s  = make_float4(0.f, 0.f, 0.f, 0.f);  // per-dim sums over this lane's 5 fields
    float  sq = 0.f;                              // sum of squares over this lane's slice
    float  xs = 0.f;                              // linear term over this lane's 5 fields

#pragma unroll
    for (int i = 0; i < 5; ++i) {
        const int f   = 4 * i + q;
        const int idx = xr[f];                    // 4 consecutive ints per wave -> 1 request
        xs += (float)idx;
        // max offset: (19*100000+99999)*64 + 63 < 2^31, int math is safe
        const int off = (f * NUM_FEATURES + idx) * LATENT + 4 * r;
        const float4 v = *reinterpret_cast<const float4*>(emb + off);
        s.x += v.x; s.y += v.y; s.z += v.z; s.w += v.w;
        sq  += v.x * v.x + v.y * v.y + v.z * v.z + v.w * v.w;
    }

    // Combine the 4 q-groups: lanes differing in bits 4,5 hold same dims, different fields.
#pragma unroll
    for (int m = 16; m < 64; m <<= 1) {
        s.x += __shfl_xor(s.x, m, 64);
        s.y += __shfl_xor(s.y, m, 64);
        s.z += __shfl_xor(s.z, m, 64);
        s.w += __shfl_xor(s.w, m, 64);
    }

    // Each dim's full sum now lives in 4 lanes (one per q) -> dot is counted 4x
    // across the wave: interaction = 0.5 * (wave_sum(dot)/4 - wave_sum(sq)).
    const float dot = s.x * s.x + s.y * s.y + s.z * s.z + s.w * s.w;
    float u = 0.125f * dot - 0.5f * sq;

    // Linear term: each field's index is replicated across 16 r-lanes; count r==0 only.
    if (r == 0) u += xs;

    // Full 64-lane reduction.
#pragma unroll
    for (int m = 32; m > 0; m >>= 1)
        u += __shfl_xor(u, m, 64);

    if (lane == 0)
        out[row] = u;
}

extern "C" void kernel_launch(void* const* d_in, const int* in_sizes, int n_in,
                              void* d_out, int out_size, void* d_ws, size_t ws_size,
                              hipStream_t stream) {
    const int*   x   = (const int*)d_in[0];
    // d_in[1] = field_indices (arange(20)) — implicit in layout
    const float* emb = (const float*)d_in[2];
    float*       out = (float*)d_out;

    const int rows_per_block = 4;                 // 256 threads / wave64
    const int grid = BATCH / rows_per_block;
    ffm_kernel<<<grid, 256, 0, stream>>>(x, emb, out);
}